// Round 8
// baseline (3270.494 us; speedup 1.0000x reference)
//
#include <hip/hip_runtime.h>
#include <hip/hip_bf16.h>

typedef unsigned short u16;
typedef unsigned int u32;
typedef unsigned long long u64;
typedef __bf16 bf16x8 __attribute__((ext_vector_type(8)));
typedef float f32x4 __attribute__((ext_vector_type(4)));

#define NB 64
#define NT 128
#define NF 1024
#define NH 1024
#define NK 2048   // F+H
#define NG 4096   // 4H
#define NBH (NB * NH)

#define SENT32 0x7F7F7F7Fu   // bf16 0x7F7F = 3.39e38, unreachable for |h|<1

// LDS: W slice 128 KiB + zsx[2 buf][2][64][17] + zsh[2][64][17]
#define W_LDS_BYTES 131072
#define ZSX_BYTES (2 * 2 * 64 * 17 * 4)   // 17408
#define ZSH_BYTES (2 * 64 * 17 * 4)       // 8704
#define SMEM_BYTES (W_LDS_BYTES + ZSX_BYTES + ZSH_BYTES)  // 157184 <= 163840

__device__ __forceinline__ u16 f2bf(float f) {
  unsigned u = __builtin_bit_cast(unsigned, f);
  u = (u + 0x7FFFu + ((u >> 16) & 1u)) >> 16;
  return (u16)u;
}
__device__ __forceinline__ float bf2f(u16 v) {
  unsigned u = ((unsigned)v) << 16;
  return __builtin_bit_cast(float, u);
}

// ---------------- prep: x fp32 -> bf16 ----------------
__global__ __launch_bounds__(256) void lstm_cvt_x(const float* __restrict__ x,
                                                  u16* __restrict__ xb) {
  int i = (blockIdx.x * 256 + threadIdx.x) * 4;
  float4 v = *reinterpret_cast<const float4*>(x + i);
  ushort4 o;
  o.x = f2bf(v.x); o.y = f2bf(v.y); o.z = f2bf(v.z); o.w = f2bf(v.w);
  *reinterpret_cast<ushort4*>(xb + i) = o;
}

// ---------------- prep: W [2048,4096] fp32 -> per-block LDS-image slices ----------------
// (verified R3-R6)  base idx: ((buf*2 + kh)*32 + ch)*512 + (slot*16 + brow)*8 + elem
__global__ __launch_bounds__(256) void lstm_prep_w(const float* __restrict__ W,
                                                   u16* __restrict__ wt_blk) {
  __shared__ float tile[32][33];
  int n0 = blockIdx.x * 32;
  int k0 = blockIdx.y * 32;
  int tc = threadIdx.x & 31;
  int tr = threadIdx.x >> 5;
#pragma unroll
  for (int i = 0; i < 4; ++i) {
    int k = tr + i * 8;
    tile[k][tc] = W[(size_t)(k0 + k) * NG + n0 + tc];
  }
  __syncthreads();
#pragma unroll
  for (int i = 0; i < 4; ++i) {
    int n = n0 + tr + i * 8;
    float wv = tile[tc][tr + i * 8];
    int k = k0 + tc;
    int g = n >> 10, col = n & 1023;
    int b = col >> 2, brow = g * 4 + (col & 3);
    int kh = k >> 10, ch = (k & 1023) >> 5;
    int slot = (k >> 3) & 3, elem = k & 7;
    size_t base = (size_t)b * 65536 + (size_t)(kh * 32 + ch) * 512
                + (size_t)(slot * 16 + brow) * 8 + elem;
    u16 hi = f2bf(wv);
    wt_blk[base] = hi;
    wt_blk[base + 32768] = f2bf(wv - bf2f(hi));
  }
}

// A-pass: 4 M-frags (rows i*16+arow), K=256 slice, hi+lo MFMA, 2-stage pipeline.
__device__ __forceinline__ void mfma_pass(const u16* __restrict__ a0, size_t rstride,
                                          const u16* __restrict__ Wl, int khalf,
                                          int kq, int lane, f32x4 acc[4]) {
  bf16x8 pf[4], qf[4];
#pragma unroll
  for (int i = 0; i < 4; ++i)
    pf[i] = *reinterpret_cast<const bf16x8*>(a0 + (size_t)i * 16 * rstride);
#pragma unroll
  for (int cc = 0; cc < 8; ++cc) {
    if (cc < 7) {
#pragma unroll
      for (int i = 0; i < 4; ++i)
        qf[i] = *reinterpret_cast<const bf16x8*>(a0 + (size_t)i * 16 * rstride + (cc + 1) * 32);
    }
    const int ch = kq * 8 + cc;
    const bf16x8 wh = *reinterpret_cast<const bf16x8*>(
        Wl + (size_t)(khalf * 32 + ch) * 512 + lane * 8);
    const bf16x8 wl2 = *reinterpret_cast<const bf16x8*>(
        Wl + (size_t)(64 + khalf * 32 + ch) * 512 + lane * 8);
#pragma unroll
    for (int i = 0; i < 4; ++i)
      acc[i] = __builtin_amdgcn_mfma_f32_16x16x32_bf16(pf[i], wh, acc[i], 0, 0, 0);
#pragma unroll
    for (int i = 0; i < 4; ++i)
      acc[i] = __builtin_amdgcn_mfma_f32_16x16x32_bf16(pf[i], wl2, acc[i], 0, 0, 0);
#pragma unroll
    for (int i = 0; i < 4; ++i) pf[i] = qf[i];
  }
}

// ---------------- persistent LSTM, sentinel-dataflow-synced ----------------
// 256 blocks x 512 threads. Waves 0-3: x-GEMM for step t+1 (zsx double buffer,
// one step ahead). Waves 4-7: h-GEMM for step t, FULL 256-wide K slice
// (8 chunks, v[64] u64). No flags: hseq pre-filled with sentinel; consumers
// poll the h data itself (agent-scope atomic loads) until non-sentinel.
__global__ __launch_bounds__(512) void lstm_persist(
    const u16* __restrict__ xb, u16* __restrict__ hseq,
    const u16* __restrict__ wt_blk, const float* __restrict__ bias,
    float* __restrict__ out) {
  extern __shared__ char smem[];
  u16* Wl = (u16*)smem;
  float (*zsx)[2][64][17] = (float(*)[2][64][17])(smem + W_LDS_BYTES);
  float (*zsh)[64][17] = (float(*)[64][17])(smem + W_LDS_BYTES + ZSX_BYTES);

  const int b = blockIdx.x;
  const int tid = threadIdx.x;
  const int lane = tid & 63;
  const int w = tid >> 6;
  const bool is_x = (w < 4);
  const int kq = w & 3;

  // ---- load W slice (128 KiB) into LDS ----
  {
    const u16* src = wt_blk + (size_t)b * 65536;
#pragma unroll
    for (int it = 0; it < 16; ++it) {
      uint4 v = *reinterpret_cast<const uint4*>(src + (size_t)it * 4096 + tid * 8);
      *reinterpret_cast<uint4*>(Wl + (size_t)it * 4096 + tid * 8) = v;
    }
  }
  // zero zsh (t=0 has no h contribution)
  for (int i = tid; i < 2 * 64 * 17; i += 512) ((float*)zsh)[i] = 0.f;

  const int arow = lane & 15;
  const int kfr = 8 * (lane >> 4);
  const int kbase = kq * 256 + kfr;
  const int zn = lane & 15;
  const int mg = (lane >> 4) * 4;

  // pointwise ownership: tid<128 owns (prow, 2 cols)
  const int prow = tid >> 1;
  const int pc = (tid & 1) * 2;
  const int gc0 = b * 4 + pc;
  float bz[2][4];
  float creg[2] = {0.f, 0.f};
  if (tid < 128) {
#pragma unroll
    for (int j = 0; j < 2; ++j) {
      bz[j][0] = bias[gc0 + j];
      bz[j][1] = bias[NH + gc0 + j];
      bz[j][2] = bias[2 * NH + gc0 + j];
      bz[j][3] = bias[3 * NH + gc0 + j];
    }
  }
  __syncthreads();

  // ---- prologue: x-waves fill zsx[0] = zx(0) ----
  {
    f32x4 acc[4] = {};
    if (is_x) {
      const u16* a0 = xb + ((size_t)arow * NT + 0) * NF + kbase;
      mfma_pass(a0, (size_t)NT * NF, Wl, 0, kq, lane, acc);
      if (w < 2) {
#pragma unroll
        for (int i = 0; i < 4; ++i)
#pragma unroll
          for (int r = 0; r < 4; ++r) zsx[0][w][i * 16 + mg + r][zn] = acc[i][r];
      }
    }
    __syncthreads();
    if (is_x && w >= 2) {
#pragma unroll
      for (int i = 0; i < 4; ++i)
#pragma unroll
        for (int r = 0; r < 4; ++r) zsx[0][w - 2][i * 16 + mg + r][zn] += acc[i][r];
    }
    __syncthreads();
  }

#pragma unroll 1
  for (int t = 0; t < NT; ++t) {
    const int cb = t & 1;        // zsx buffer consumed this step
    const int nb = (t + 1) & 1;  // zsx buffer filled this step
    f32x4 acc[4] = {};

    if (is_x) {
      if (t < NT - 1) {
        const u16* a0 = xb + ((size_t)arow * NT + (t + 1)) * NF + kbase;
        mfma_pass(a0, (size_t)NT * NF, Wl, 0, kq, lane, acc);
      }
    } else {
      if (t > 0) {
        // ---- sentinel data-poll over the FULL K=256 slice (8 chunks) ----
        const u16* h0 = hseq + (size_t)t * NBH + (size_t)arow * NH + kbase;
        u64 v[64];
        while (true) {
#pragma unroll
          for (int cc = 0; cc < 8; ++cc)
#pragma unroll
            for (int i = 0; i < 4; ++i) {
              const u64* p = reinterpret_cast<const u64*>(
                  h0 + (size_t)i * 16 * NH + cc * 32);
              v[(cc * 4 + i) * 2 + 0] =
                  __hip_atomic_load(p + 0, __ATOMIC_RELAXED, __HIP_MEMORY_SCOPE_AGENT);
              v[(cc * 4 + i) * 2 + 1] =
                  __hip_atomic_load(p + 1, __ATOMIC_RELAXED, __HIP_MEMORY_SCOPE_AGENT);
            }
          unsigned bad = 0;
#pragma unroll
          for (int k2 = 0; k2 < 64; ++k2) {
            bad |= ((u32)v[k2] == SENT32);
            bad |= ((u32)(v[k2] >> 32) == SENT32);
          }
          if (__all(bad == 0)) break;
        }
        // ---- h-GEMM from registers (8 chunks = full 256-wide slice) ----
        __builtin_amdgcn_s_setprio(1);
#pragma unroll
        for (int cc = 0; cc < 8; ++cc) {
          const int ch = kq * 8 + cc;
          const bf16x8 wh = *reinterpret_cast<const bf16x8*>(
              Wl + (size_t)(32 + ch) * 512 + lane * 8);             // kh=1 hi
          const bf16x8 wlo = *reinterpret_cast<const bf16x8*>(
              Wl + (size_t)(96 + ch) * 512 + lane * 8);             // kh=1 lo
#pragma unroll
          for (int i = 0; i < 4; ++i) {
            union HU { u64 q[2]; bf16x8 f; } u;
            u.q[0] = v[(cc * 4 + i) * 2 + 0];
            u.q[1] = v[(cc * 4 + i) * 2 + 1];
            acc[i] = __builtin_amdgcn_mfma_f32_16x16x32_bf16(u.f, wh, acc[i], 0, 0, 0);
            acc[i] = __builtin_amdgcn_mfma_f32_16x16x32_bf16(u.f, wlo, acc[i], 0, 0, 0);
          }
        }
        __builtin_amdgcn_s_setprio(0);
      }
    }

    __syncthreads();  // sync1: previous pointwise done -> zs free
    if (is_x) {
      if (w < 2 && t < NT - 1) {
#pragma unroll
        for (int i = 0; i < 4; ++i)
#pragma unroll
          for (int r = 0; r < 4; ++r) zsx[nb][w][i * 16 + mg + r][zn] = acc[i][r];
      }
    } else {
      if (w < 6 && t > 0) {
#pragma unroll
        for (int i = 0; i < 4; ++i)
#pragma unroll
          for (int r = 0; r < 4; ++r) zsh[w - 4][i * 16 + mg + r][zn] = acc[i][r];
      }
    }
    __syncthreads();  // sync2
    if (is_x) {
      if (w >= 2 && t < NT - 1) {
#pragma unroll
        for (int i = 0; i < 4; ++i)
#pragma unroll
          for (int r = 0; r < 4; ++r) zsx[nb][w - 2][i * 16 + mg + r][zn] += acc[i][r];
      }
    } else {
      if (w >= 6 && t > 0) {
#pragma unroll
        for (int i = 0; i < 4; ++i)
#pragma unroll
          for (int r = 0; r < 4; ++r) zsh[w - 6][i * 16 + mg + r][zn] += acc[i][r];
      }
    }
    __syncthreads();  // sync3

    // ---- fused pointwise + h publish (store IS the signal) ----
    if (tid < 128) {
      float hn[2];
#pragma unroll
      for (int jj = 0; jj < 2; ++jj) {
        const int col = pc + jj;
        const float zi = zsx[cb][0][prow][col]      + zsx[cb][1][prow][col]      + zsh[0][prow][col]      + zsh[1][prow][col]      + bz[jj][0];
        const float zj = zsx[cb][0][prow][4 + col]  + zsx[cb][1][prow][4 + col]  + zsh[0][prow][4 + col]  + zsh[1][prow][4 + col]  + bz[jj][1];
        const float zf = zsx[cb][0][prow][8 + col]  + zsx[cb][1][prow][8 + col]  + zsh[0][prow][8 + col]  + zsh[1][prow][8 + col]  + bz[jj][2];
        const float zo = zsx[cb][0][prow][12 + col] + zsx[cb][1][prow][12 + col] + zsh[0][prow][12 + col] + zsh[1][prow][12 + col] + bz[jj][3];
        const float si = 1.f / (1.f + __expf(-zi));
        const float tj = tanhf(zj);
        const float sf = 1.f / (1.f + __expf(-(zf + 1.0f)));  // FORGET_BIAS = 1
        const float so = 1.f / (1.f + __expf(-zo));
        const float cn = creg[jj] * sf + si * tj;
        hn[jj] = tanhf(cn) * so;
        creg[jj] = cn;
      }
      float2 ov = {hn[0], hn[1]};
      *reinterpret_cast<float2*>(out + ((size_t)prow * NT + t) * NH + gc0) = ov;
      if (t < NT - 1) {
        u32 hv = (u32)f2bf(hn[0]) | ((u32)f2bf(hn[1]) << 16);
        __hip_atomic_store(
            reinterpret_cast<u32*>(hseq + (size_t)(t + 1) * NBH + (size_t)prow * NH + gc0),
            hv, __ATOMIC_RELAXED, __HIP_MEMORY_SCOPE_AGENT);
      }
    }
    // no tail: consumers poll the data directly
  }
}

extern "C" void kernel_launch(void* const* d_in, const int* in_sizes, int n_in,
                              void* d_out, int out_size, void* d_ws, size_t ws_size,
                              hipStream_t stream) {
  const float* x = (const float*)d_in[0];
  const float* W = (const float*)d_in[1];
  const float* bias = (const float*)d_in[2];
  float* out = (float*)d_out;

  char* ws = (char*)d_ws;
  u16* xb = (u16*)(ws);                                  // 16 MiB
  u16* wt_blk = (u16*)(ws + 16777216);                   // 32 MiB
  u16* hseq = (u16*)(ws + 50331648);                     // 128 * 128 KiB = 16 MiB

  // fill ALL h slabs with the sentinel (slab 0 is never read; stores go to 1..127)
  hipMemsetAsync(hseq, 0x7F, (size_t)NT * NBH * sizeof(u16), stream);

  lstm_cvt_x<<<(NB * NT * NF) / (256 * 4), 256, 0, stream>>>(x, xb);
  lstm_prep_w<<<dim3(NG / 32, NK / 32), 256, 0, stream>>>(W, wt_blk);

  hipFuncSetAttribute((const void*)lstm_persist,
                      hipFuncAttributeMaxDynamicSharedMemorySize, SMEM_BYTES);

  void* args[] = {(void*)&xb, (void*)&hseq, (void*)&wt_blk, (void*)&bias,
                  (void*)&out};
  hipLaunchCooperativeKernel((void*)lstm_persist, dim3(256), dim3(512), args,
                             SMEM_BYTES, stream);
}

// Round 9
// 1719.607 us; speedup vs baseline: 1.9019x; 1.9019x over previous
//
#include <hip/hip_runtime.h>
#include <hip/hip_bf16.h>

typedef unsigned short u16;
typedef unsigned int u32;
typedef unsigned long long u64;
typedef __bf16 bf16x8 __attribute__((ext_vector_type(8)));
typedef float f32x4 __attribute__((ext_vector_type(4)));

#define NB 64
#define NT 128
#define NF 1024
#define NH 1024
#define NK 2048   // F+H
#define NG 4096   // 4H
#define NBH (NB * NH)

#define SENT32 0x7F7F7F7Fu   // bf16 0x7F7F = 3.39e38, unreachable for |h|<1

// LDS: W slice 128 KiB + zsx[2 buf][2][64][17] + zsh[2][64][17]
#define W_LDS_BYTES 131072
#define ZSX_BYTES (2 * 2 * 64 * 17 * 4)   // 17408
#define ZSH_BYTES (2 * 64 * 17 * 4)       // 8704
#define SMEM_BYTES (W_LDS_BYTES + ZSX_BYTES + ZSH_BYTES)  // 157184 <= 163840

__device__ __forceinline__ u16 f2bf(float f) {
  unsigned u = __builtin_bit_cast(unsigned, f);
  u = (u + 0x7FFFu + ((u >> 16) & 1u)) >> 16;
  return (u16)u;
}
__device__ __forceinline__ float bf2f(u16 v) {
  unsigned u = ((unsigned)v) << 16;
  return __builtin_bit_cast(float, u);
}

// ---------------- prep: x fp32 -> bf16 ----------------
__global__ __launch_bounds__(256) void lstm_cvt_x(const float* __restrict__ x,
                                                  u16* __restrict__ xb) {
  int i = (blockIdx.x * 256 + threadIdx.x) * 4;
  float4 v = *reinterpret_cast<const float4*>(x + i);
  ushort4 o;
  o.x = f2bf(v.x); o.y = f2bf(v.y); o.z = f2bf(v.z); o.w = f2bf(v.w);
  *reinterpret_cast<ushort4*>(xb + i) = o;
}

// ---------------- prep: W [2048,4096] fp32 -> per-block LDS-image slices ----------------
// (verified R3-R8)  base idx: ((buf*2 + kh)*32 + ch)*512 + (slot*16 + brow)*8 + elem
__global__ __launch_bounds__(256) void lstm_prep_w(const float* __restrict__ W,
                                                   u16* __restrict__ wt_blk) {
  __shared__ float tile[32][33];
  int n0 = blockIdx.x * 32;
  int k0 = blockIdx.y * 32;
  int tc = threadIdx.x & 31;
  int tr = threadIdx.x >> 5;
#pragma unroll
  for (int i = 0; i < 4; ++i) {
    int k = tr + i * 8;
    tile[k][tc] = W[(size_t)(k0 + k) * NG + n0 + tc];
  }
  __syncthreads();
#pragma unroll
  for (int i = 0; i < 4; ++i) {
    int n = n0 + tr + i * 8;
    float wv = tile[tc][tr + i * 8];
    int k = k0 + tc;
    int g = n >> 10, col = n & 1023;
    int b = col >> 2, brow = g * 4 + (col & 3);
    int kh = k >> 10, ch = (k & 1023) >> 5;
    int slot = (k >> 3) & 3, elem = k & 7;
    size_t base = (size_t)b * 65536 + (size_t)(kh * 32 + ch) * 512
                + (size_t)(slot * 16 + brow) * 8 + elem;
    u16 hi = f2bf(wv);
    wt_blk[base] = hi;
    wt_blk[base + 32768] = f2bf(wv - bf2f(hi));
  }
}

// A-pass: 4 M-frags (rows i*16+arow), K=256 slice, hi+lo MFMA, 2-stage pipeline.
__device__ __forceinline__ void mfma_pass(const u16* __restrict__ a0, size_t rstride,
                                          const u16* __restrict__ Wl, int khalf,
                                          int kq, int lane, f32x4 acc[4]) {
  bf16x8 pf[4], qf[4];
#pragma unroll
  for (int i = 0; i < 4; ++i)
    pf[i] = *reinterpret_cast<const bf16x8*>(a0 + (size_t)i * 16 * rstride);
#pragma unroll
  for (int cc = 0; cc < 8; ++cc) {
    if (cc < 7) {
#pragma unroll
      for (int i = 0; i < 4; ++i)
        qf[i] = *reinterpret_cast<const bf16x8*>(a0 + (size_t)i * 16 * rstride + (cc + 1) * 32);
    }
    const int ch = kq * 8 + cc;
    const bf16x8 wh = *reinterpret_cast<const bf16x8*>(
        Wl + (size_t)(khalf * 32 + ch) * 512 + lane * 8);
    const bf16x8 wl2 = *reinterpret_cast<const bf16x8*>(
        Wl + (size_t)(64 + khalf * 32 + ch) * 512 + lane * 8);
#pragma unroll
    for (int i = 0; i < 4; ++i)
      acc[i] = __builtin_amdgcn_mfma_f32_16x16x32_bf16(pf[i], wh, acc[i], 0, 0, 0);
#pragma unroll
    for (int i = 0; i < 4; ++i)
      acc[i] = __builtin_amdgcn_mfma_f32_16x16x32_bf16(pf[i], wl2, acc[i], 0, 0, 0);
#pragma unroll
    for (int i = 0; i < 4; ++i) pf[i] = qf[i];
  }
}

// ---------------- persistent LSTM, canary-dataflow-synced ----------------
// 256 blocks x 512 threads. Waves 0-3: x-GEMM for step t+1 (zsx double buffer,
// one step ahead). Waves 4-7: h-GEMM for step t, K=256 slice.
// Producer: bare relaxed-agent u32 h-stores (write-through to LLC), no ack,
// no flag. Consumer: (1) canary gate — lane L spins on ONE u32 of producer
// block 64kq+L (256 B/iter/wave, cheap like a flag poll); (2) ONE bulk plain
// load of the 32 KB slice (fresh lines -> never stale); (3) sentinel verify
// with selective atomic retry (covers unordered store arrival + any stale-
// sentinel L2 pollution from early plain loads).
__global__ __launch_bounds__(512) void lstm_persist(
    const u16* __restrict__ xb, u16* __restrict__ hseq,
    const u16* __restrict__ wt_blk, const float* __restrict__ bias,
    float* __restrict__ out) {
  extern __shared__ char smem[];
  u16* Wl = (u16*)smem;
  float (*zsx)[2][64][17] = (float(*)[2][64][17])(smem + W_LDS_BYTES);
  float (*zsh)[64][17] = (float(*)[64][17])(smem + W_LDS_BYTES + ZSX_BYTES);

  const int b = blockIdx.x;
  const int tid = threadIdx.x;
  const int lane = tid & 63;
  const int w = tid >> 6;
  const bool is_x = (w < 4);
  const int kq = w & 3;

  // ---- load W slice (128 KiB) into LDS ----
  {
    const u16* src = wt_blk + (size_t)b * 65536;
#pragma unroll
    for (int it = 0; it < 16; ++it) {
      uint4 v = *reinterpret_cast<const uint4*>(src + (size_t)it * 4096 + tid * 8);
      *reinterpret_cast<uint4*>(Wl + (size_t)it * 4096 + tid * 8) = v;
    }
  }
  // zero zsh (t=0 has no h contribution)
  for (int i = tid; i < 2 * 64 * 17; i += 512) ((float*)zsh)[i] = 0.f;

  const int arow = lane & 15;
  const int kfr = 8 * (lane >> 4);
  const int kbase = kq * 256 + kfr;
  const int zn = lane & 15;
  const int mg = (lane >> 4) * 4;

  // pointwise ownership: tid<128 owns (prow, 2 cols)
  const int prow = tid >> 1;
  const int pc = (tid & 1) * 2;
  const int gc0 = b * 4 + pc;
  float bz[2][4];
  float creg[2] = {0.f, 0.f};
  if (tid < 128) {
#pragma unroll
    for (int j = 0; j < 2; ++j) {
      bz[j][0] = bias[gc0 + j];
      bz[j][1] = bias[NH + gc0 + j];
      bz[j][2] = bias[2 * NH + gc0 + j];
      bz[j][3] = bias[3 * NH + gc0 + j];
    }
  }
  __syncthreads();

  // ---- prologue: x-waves fill zsx[0] = zx(0) ----
  {
    f32x4 acc[4] = {};
    if (is_x) {
      const u16* a0 = xb + ((size_t)arow * NT + 0) * NF + kbase;
      mfma_pass(a0, (size_t)NT * NF, Wl, 0, kq, lane, acc);
      if (w < 2) {
#pragma unroll
        for (int i = 0; i < 4; ++i)
#pragma unroll
          for (int r = 0; r < 4; ++r) zsx[0][w][i * 16 + mg + r][zn] = acc[i][r];
      }
    }
    __syncthreads();
    if (is_x && w >= 2) {
#pragma unroll
      for (int i = 0; i < 4; ++i)
#pragma unroll
        for (int r = 0; r < 4; ++r) zsx[0][w - 2][i * 16 + mg + r][zn] += acc[i][r];
    }
    __syncthreads();
  }

#pragma unroll 1
  for (int t = 0; t < NT; ++t) {
    const int cb = t & 1;        // zsx buffer consumed this step
    const int nb = (t + 1) & 1;  // zsx buffer filled this step
    f32x4 acc[4] = {};

    if (is_x) {
      if (t < NT - 1) {
        const u16* a0 = xb + ((size_t)arow * NT + (t + 1)) * NF + kbase;
        mfma_pass(a0, (size_t)NT * NF, Wl, 0, kq, lane, acc);
      }
    } else {
      if (t > 0) {
        const u16* h0 = hseq + (size_t)t * NBH + (size_t)arow * NH + kbase;

        // ---- (1) canary gate: lane L watches producer block p = 64kq+L ----
        // producer p's thread 127 atomically stores the u32 covering
        // h[row 63][cols 4p+2..4p+3]  -> u32 index 2p+1 within row 63.
        {
          const int p = kq * 64 + lane;
          const u32* cp = reinterpret_cast<const u32*>(
              hseq + (size_t)t * NBH + (size_t)63 * NH) + (2 * p + 1);
          u32 cv;
          do {
            cv = __hip_atomic_load(cp, __ATOMIC_RELAXED, __HIP_MEMORY_SCOPE_AGENT);
          } while (!__all(cv != SENT32));
        }

        // ---- (2) one bulk plain load: 8 chunks x 4 m-frags x 16 B ----
        uint4 v[32];
#pragma unroll
        for (int cc = 0; cc < 8; ++cc)
#pragma unroll
          for (int i = 0; i < 4; ++i)
            v[cc * 4 + i] = *reinterpret_cast<const uint4*>(
                h0 + (size_t)i * 16 * NH + cc * 32);

        // ---- (3) verify + selective atomic retry until a clean pass ----
        while (true) {
          u32 anybad = 0;
#pragma unroll
          for (int cc = 0; cc < 8; ++cc) {
#pragma unroll
            for (int i = 0; i < 4; ++i) {
              uint4& f = v[cc * 4 + i];
              u32 bad = (f.x == SENT32) | (f.y == SENT32) |
                        (f.z == SENT32) | (f.w == SENT32);
              if (bad) {
                const u64* p = reinterpret_cast<const u64*>(
                    h0 + (size_t)i * 16 * NH + cc * 32);
                u64 lo = __hip_atomic_load(p + 0, __ATOMIC_RELAXED,
                                           __HIP_MEMORY_SCOPE_AGENT);
                u64 hi = __hip_atomic_load(p + 1, __ATOMIC_RELAXED,
                                           __HIP_MEMORY_SCOPE_AGENT);
                f.x = (u32)lo; f.y = (u32)(lo >> 32);
                f.z = (u32)hi; f.w = (u32)(hi >> 32);
              }
              anybad |= bad;
            }
          }
          if (__all(anybad == 0)) break;
        }

        // ---- h-GEMM from registers (8 chunks = full 256-wide slice) ----
        __builtin_amdgcn_s_setprio(1);
#pragma unroll
        for (int cc = 0; cc < 8; ++cc) {
          const int ch = kq * 8 + cc;
          const bf16x8 wh = *reinterpret_cast<const bf16x8*>(
              Wl + (size_t)(32 + ch) * 512 + lane * 8);             // kh=1 hi
          const bf16x8 wlo = *reinterpret_cast<const bf16x8*>(
              Wl + (size_t)(96 + ch) * 512 + lane * 8);             // kh=1 lo
#pragma unroll
          for (int i = 0; i < 4; ++i) {
            union HU { uint4 q; bf16x8 f; } u;
            u.q = v[cc * 4 + i];
            acc[i] = __builtin_amdgcn_mfma_f32_16x16x32_bf16(u.f, wh, acc[i], 0, 0, 0);
            acc[i] = __builtin_amdgcn_mfma_f32_16x16x32_bf16(u.f, wlo, acc[i], 0, 0, 0);
          }
        }
        __builtin_amdgcn_s_setprio(0);
      }
    }

    __syncthreads();  // sync1: previous pointwise done -> zs free
    if (is_x) {
      if (w < 2 && t < NT - 1) {
#pragma unroll
        for (int i = 0; i < 4; ++i)
#pragma unroll
          for (int r = 0; r < 4; ++r) zsx[nb][w][i * 16 + mg + r][zn] = acc[i][r];
      }
    } else {
      if (w < 6 && t > 0) {
#pragma unroll
        for (int i = 0; i < 4; ++i)
#pragma unroll
          for (int r = 0; r < 4; ++r) zsh[w - 4][i * 16 + mg + r][zn] = acc[i][r];
      }
    }
    __syncthreads();  // sync2
    if (is_x) {
      if (w >= 2 && t < NT - 1) {
#pragma unroll
        for (int i = 0; i < 4; ++i)
#pragma unroll
          for (int r = 0; r < 4; ++r) zsx[nb][w - 2][i * 16 + mg + r][zn] += acc[i][r];
      }
    } else {
      if (w >= 6 && t > 0) {
#pragma unroll
        for (int i = 0; i < 4; ++i)
#pragma unroll
          for (int r = 0; r < 4; ++r) zsh[w - 6][i * 16 + mg + r][zn] += acc[i][r];
      }
    }
    __syncthreads();  // sync3

    // ---- fused pointwise + h publish (store IS the signal) ----
    if (tid < 128) {
      float hn[2];
#pragma unroll
      for (int jj = 0; jj < 2; ++jj) {
        const int col = pc + jj;
        const float zi = zsx[cb][0][prow][col]      + zsx[cb][1][prow][col]      + zsh[0][prow][col]      + zsh[1][prow][col]      + bz[jj][0];
        const float zj = zsx[cb][0][prow][4 + col]  + zsx[cb][1][prow][4 + col]  + zsh[0][prow][4 + col]  + zsh[1][prow][4 + col]  + bz[jj][1];
        const float zf = zsx[cb][0][prow][8 + col]  + zsx[cb][1][prow][8 + col]  + zsh[0][prow][8 + col]  + zsh[1][prow][8 + col]  + bz[jj][2];
        const float zo = zsx[cb][0][prow][12 + col] + zsx[cb][1][prow][12 + col] + zsh[0][prow][12 + col] + zsh[1][prow][12 + col] + bz[jj][3];
        const float si = 1.f / (1.f + __expf(-zi));
        const float tj = tanhf(zj);
        const float sf = 1.f / (1.f + __expf(-(zf + 1.0f)));  // FORGET_BIAS = 1
        const float so = 1.f / (1.f + __expf(-zo));
        const float cn = creg[jj] * sf + si * tj;
        hn[jj] = tanhf(cn) * so;
        creg[jj] = cn;
      }
      float2 ov = {hn[0], hn[1]};
      *reinterpret_cast<float2*>(out + ((size_t)prow * NT + t) * NH + gc0) = ov;
      if (t < NT - 1) {
        u32 hv = (u32)f2bf(hn[0]) | ((u32)f2bf(hn[1]) << 16);
        __hip_atomic_store(
            reinterpret_cast<u32*>(hseq + (size_t)(t + 1) * NBH + (size_t)prow * NH + gc0),
            hv, __ATOMIC_RELAXED, __HIP_MEMORY_SCOPE_AGENT);
      }
    }
    // no tail: consumers gate on the data itself
  }
}

extern "C" void kernel_launch(void* const* d_in, const int* in_sizes, int n_in,
                              void* d_out, int out_size, void* d_ws, size_t ws_size,
                              hipStream_t stream) {
  const float* x = (const float*)d_in[0];
  const float* W = (const float*)d_in[1];
  const float* bias = (const float*)d_in[2];
  float* out = (float*)d_out;

  char* ws = (char*)d_ws;
  u16* xb = (u16*)(ws);                                  // 16 MiB
  u16* wt_blk = (u16*)(ws + 16777216);                   // 32 MiB
  u16* hseq = (u16*)(ws + 50331648);                     // 128 * 128 KiB = 16 MiB

  // fill ALL h slabs with the sentinel (slab 0 is never read; stores go to 1..127)
  hipMemsetAsync(hseq, 0x7F, (size_t)NT * NBH * sizeof(u16), stream);

  lstm_cvt_x<<<(NB * NT * NF) / (256 * 4), 256, 0, stream>>>(x, xb);
  lstm_prep_w<<<dim3(NG / 32, NK / 32), 256, 0, stream>>>(W, wt_blk);

  hipFuncSetAttribute((const void*)lstm_persist,
                      hipFuncAttributeMaxDynamicSharedMemorySize, SMEM_BYTES);

  void* args[] = {(void*)&xb, (void*)&hseq, (void*)&wt_blk, (void*)&bias,
                  (void*)&out};
  hipLaunchCooperativeKernel((void*)lstm_persist, dim3(256), dim3(512), args,
                             SMEM_BYTES, stream);
}

// Round 10
// 1601.612 us; speedup vs baseline: 2.0420x; 1.0737x over previous
//
#include <hip/hip_runtime.h>
#include <hip/hip_bf16.h>

typedef unsigned short u16;
typedef unsigned int u32;
typedef unsigned long long u64;
typedef __bf16 bf16x8 __attribute__((ext_vector_type(8)));
typedef float f32x4 __attribute__((ext_vector_type(4)));

#define NB 64
#define NT 128
#define NF 1024
#define NH 1024
#define NK 2048   // F+H
#define NG 4096   // 4H
#define NBH (NB * NH)

// LDS: W 128 KiB + zsx[2][2][64][17] + zsh[2][64][17] + stamps
#define W_LDS_BYTES 131072
#define ZSX_BYTES (2 * 2 * 64 * 17 * 4)   // 17408
#define ZSH_BYTES (2 * 64 * 17 * 4)       // 8704
#define ST_BYTES 64
#define SMEM_BYTES (W_LDS_BYTES + ZSX_BYTES + ZSH_BYTES + ST_BYTES)  // 157248

// stamp slots (all monotonic, single-writer, init 0):
// st[0..1]=xs_w  st[2..3]=xs_a  st[4..5]=hs_w  st[6..7]=hs_a  st[8..9]=pw
__device__ __forceinline__ void st_rel(u32* p, u32 v) {
  __hip_atomic_store(p, v, __ATOMIC_RELEASE, __HIP_MEMORY_SCOPE_WORKGROUP);
}
__device__ __forceinline__ u32 ld_acq(u32* p) {
  return __hip_atomic_load(p, __ATOMIC_ACQUIRE, __HIP_MEMORY_SCOPE_WORKGROUP);
}
__device__ __forceinline__ void spin_ge(u32* p, u32 v) {
  while (ld_acq(p) < v) {}
}

__device__ __forceinline__ u16 f2bf(float f) {
  unsigned u = __builtin_bit_cast(unsigned, f);
  u = (u + 0x7FFFu + ((u >> 16) & 1u)) >> 16;
  return (u16)u;
}
__device__ __forceinline__ float bf2f(u16 v) {
  unsigned u = ((unsigned)v) << 16;
  return __builtin_bit_cast(float, u);
}

// ---------------- prep: x fp32 -> bf16 ----------------
__global__ __launch_bounds__(256) void lstm_cvt_x(const float* __restrict__ x,
                                                  u16* __restrict__ xb) {
  int i = (blockIdx.x * 256 + threadIdx.x) * 4;
  float4 v = *reinterpret_cast<const float4*>(x + i);
  ushort4 o;
  o.x = f2bf(v.x); o.y = f2bf(v.y); o.z = f2bf(v.z); o.w = f2bf(v.w);
  *reinterpret_cast<ushort4*>(xb + i) = o;
}

// ---------------- prep: W [2048,4096] fp32 -> per-block LDS-image slices ----------------
// (verified R3-R9)  base idx: ((buf*2 + kh)*32 + ch)*512 + (slot*16 + brow)*8 + elem
__global__ __launch_bounds__(256) void lstm_prep_w(const float* __restrict__ W,
                                                   u16* __restrict__ wt_blk) {
  __shared__ float tile[32][33];
  int n0 = blockIdx.x * 32;
  int k0 = blockIdx.y * 32;
  int tc = threadIdx.x & 31;
  int tr = threadIdx.x >> 5;
#pragma unroll
  for (int i = 0; i < 4; ++i) {
    int k = tr + i * 8;
    tile[k][tc] = W[(size_t)(k0 + k) * NG + n0 + tc];
  }
  __syncthreads();
#pragma unroll
  for (int i = 0; i < 4; ++i) {
    int n = n0 + tr + i * 8;
    float wv = tile[tc][tr + i * 8];
    int k = k0 + tc;
    int g = n >> 10, col = n & 1023;
    int b = col >> 2, brow = g * 4 + (col & 3);
    int kh = k >> 10, ch = (k & 1023) >> 5;
    int slot = (k >> 3) & 3, elem = k & 7;
    size_t base = (size_t)b * 65536 + (size_t)(kh * 32 + ch) * 512
                + (size_t)(slot * 16 + brow) * 8 + elem;
    u16 hi = f2bf(wv);
    wt_blk[base] = hi;
    wt_blk[base + 32768] = f2bf(wv - bf2f(hi));
  }
}

// A-pass: 4 M-frags (rows i*16+arow), K=256 slice, hi+lo MFMA, 2-stage pipeline.
__device__ __forceinline__ void mfma_pass(const u16* __restrict__ a0, size_t rstride,
                                          const u16* __restrict__ Wl, int khalf,
                                          int kq, int lane, f32x4 acc[4]) {
  bf16x8 pf[4], qf[4];
#pragma unroll
  for (int i = 0; i < 4; ++i)
    pf[i] = *reinterpret_cast<const bf16x8*>(a0 + (size_t)i * 16 * rstride);
#pragma unroll
  for (int cc = 0; cc < 8; ++cc) {
    if (cc < 7) {
#pragma unroll
      for (int i = 0; i < 4; ++i)
        qf[i] = *reinterpret_cast<const bf16x8*>(a0 + (size_t)i * 16 * rstride + (cc + 1) * 32);
    }
    const int ch = kq * 8 + cc;
    const bf16x8 wh = *reinterpret_cast<const bf16x8*>(
        Wl + (size_t)(khalf * 32 + ch) * 512 + lane * 8);
    const bf16x8 wl2 = *reinterpret_cast<const bf16x8*>(
        Wl + (size_t)(64 + khalf * 32 + ch) * 512 + lane * 8);
#pragma unroll
    for (int i = 0; i < 4; ++i)
      acc[i] = __builtin_amdgcn_mfma_f32_16x16x32_bf16(pf[i], wh, acc[i], 0, 0, 0);
#pragma unroll
    for (int i = 0; i < 4; ++i)
      acc[i] = __builtin_amdgcn_mfma_f32_16x16x32_bf16(pf[i], wl2, acc[i], 0, 0, 0);
#pragma unroll
    for (int i = 0; i < 4; ++i) pf[i] = qf[i];
  }
}

// ---------------- persistent LSTM, barrier-free step loop ----------------
// 256 blocks x 512 threads. NO __syncthreads in the step loop; all intra-block
// ordering via monotonic single-writer LDS stamps (release/acquire ds ops).
// Waves 0-3: x-GEMM for step t into zsx[t&1], gated only by pw >= t-1.
// Waves 4-7: poll flags[t] -> bulk PLAIN h load -> MFMA -> zsh stamps.
// Waves 4-5: pointwise, h publish (atomic stores), vmcnt(0), pw stamp;
// wave 4 stores flags[t+1][b] after both pw stamps => flag PROVES all h at LLC
// => plain consumer loads can never cache stale data. No sentinel, no retry.
__global__ __launch_bounds__(512) void lstm_persist(
    const u16* __restrict__ xb, u16* __restrict__ hseq,
    const u16* __restrict__ wt_blk, const float* __restrict__ bias,
    float* __restrict__ out, u32* __restrict__ flags) {
  extern __shared__ char smem[];
  u16* Wl = (u16*)smem;
  float (*zsx)[2][64][17] = (float(*)[2][64][17])(smem + W_LDS_BYTES);
  float (*zsh)[64][17] = (float(*)[64][17])(smem + W_LDS_BYTES + ZSX_BYTES);
  u32* st = (u32*)(smem + W_LDS_BYTES + ZSX_BYTES + ZSH_BYTES);

  const int b = blockIdx.x;
  const int tid = threadIdx.x;
  const int lane = tid & 63;
  const int w = tid >> 6;
  const bool is_x = (w < 4);
  const int kq = w & 3;

  // ---- load W slice (128 KiB) into LDS ----
  {
    const u16* src = wt_blk + (size_t)b * 65536;
#pragma unroll
    for (int it = 0; it < 16; ++it) {
      uint4 v = *reinterpret_cast<const uint4*>(src + (size_t)it * 4096 + tid * 8);
      *reinterpret_cast<uint4*>(Wl + (size_t)it * 4096 + tid * 8) = v;
    }
  }
  // zero zsh (t=0 has no h contribution) and stamps
  for (int i = tid; i < 2 * 64 * 17; i += 512) ((float*)zsh)[i] = 0.f;
  if (tid < 16) st[tid] = 0u;

  const int arow = lane & 15;
  const int kfr = 8 * (lane >> 4);
  const int kbase = kq * 256 + kfr;
  const int zn = lane & 15;
  const int mg = (lane >> 4) * 4;

  // pointwise ownership (waves 4,5): idx = (w-4)*64 + lane -> (prow, 2 cols)
  const int hq = w - 4;
  const int idx = hq * 64 + lane;
  const int prow = idx >> 1;
  const int pc = (idx & 1) * 2;
  const int gc0 = b * 4 + pc;
  float bz[2][4];
  float creg[2] = {0.f, 0.f};
  if (w == 4 || w == 5) {
#pragma unroll
    for (int j = 0; j < 2; ++j) {
      bz[j][0] = bias[gc0 + j];
      bz[j][1] = bias[NH + gc0 + j];
      bz[j][2] = bias[2 * NH + gc0 + j];
      bz[j][3] = bias[3 * NH + gc0 + j];
    }
  }
  __syncthreads();  // prologue only

#pragma unroll 1
  for (int t = 0; t < NT; ++t) {
    if (is_x) {
      // ---- x-GEMM for step t into zsx[t&1]; gate: pointwise(t-2) done ----
      const u32 vreq = (t < 2) ? 0u : (u32)(t - 1);
      spin_ge(&st[8], vreq);
      spin_ge(&st[9], vreq);
      f32x4 acc[4] = {};
      const u16* a0 = xb + ((size_t)arow * NT + t) * NF + kbase;
      mfma_pass(a0, (size_t)NT * NF, Wl, 0, kq, lane, acc);
      const int buf = t & 1;
      if (w < 2) {
#pragma unroll
        for (int i = 0; i < 4; ++i)
#pragma unroll
          for (int r = 0; r < 4; ++r) zsx[buf][w][i * 16 + mg + r][zn] = acc[i][r];
        st_rel(&st[0 + w], (u32)(t + 1));
      } else {
        spin_ge(&st[0 + (w - 2)], (u32)(t + 1));
#pragma unroll
        for (int i = 0; i < 4; ++i)
#pragma unroll
          for (int r = 0; r < 4; ++r) zsx[buf][w - 2][i * 16 + mg + r][zn] += acc[i][r];
        st_rel(&st[2 + (w - 2)], (u32)(t + 1));
      }
    } else {
      // ---- h-GEMM for step t (K-quarter kq) ----
      f32x4 acc[4] = {};
      if (t > 0) {
        const u32* fp = flags + (size_t)t * 256 + kq * 64 + lane;
        u32 fv;
        do {
          fv = __hip_atomic_load(fp, __ATOMIC_RELAXED, __HIP_MEMORY_SCOPE_AGENT);
        } while (!__all(fv != 0));
        // bulk PLAIN load (flag proves data at LLC; L2 fills are fresh)
        const u16* h0 = hseq + (size_t)t * NBH + (size_t)arow * NH + kbase;
        uint4 v[32];
#pragma unroll
        for (int cc = 0; cc < 8; ++cc)
#pragma unroll
          for (int i = 0; i < 4; ++i)
            v[cc * 4 + i] = *reinterpret_cast<const uint4*>(
                h0 + (size_t)i * 16 * NH + cc * 32);
        __builtin_amdgcn_s_setprio(1);
#pragma unroll
        for (int cc = 0; cc < 8; ++cc) {
          const int ch = kq * 8 + cc;
          const bf16x8 wh = *reinterpret_cast<const bf16x8*>(
              Wl + (size_t)(32 + ch) * 512 + lane * 8);             // kh=1 hi
          const bf16x8 wlo = *reinterpret_cast<const bf16x8*>(
              Wl + (size_t)(96 + ch) * 512 + lane * 8);             // kh=1 lo
#pragma unroll
          for (int i = 0; i < 4; ++i) {
            union HU { uint4 q; bf16x8 f; } u;
            u.q = v[cc * 4 + i];
            acc[i] = __builtin_amdgcn_mfma_f32_16x16x32_bf16(u.f, wh, acc[i], 0, 0, 0);
            acc[i] = __builtin_amdgcn_mfma_f32_16x16x32_bf16(u.f, wlo, acc[i], 0, 0, 0);
          }
        }
        __builtin_amdgcn_s_setprio(0);
      }

      // ---- zsh exchange via stamps ----
      if (hq < 2) {
        // writer: ensure the OTHER pointwise wave finished reading zsh (t-1)
        spin_ge(&st[8 + (1 - hq)], (u32)t);
        if (t > 0) {
#pragma unroll
          for (int i = 0; i < 4; ++i)
#pragma unroll
            for (int r = 0; r < 4; ++r) zsh[hq][i * 16 + mg + r][zn] = acc[i][r];
        }
        st_rel(&st[4 + hq], (u32)(t + 1));
      } else {
        spin_ge(&st[4 + (hq - 2)], (u32)(t + 1));
        if (t > 0) {
#pragma unroll
          for (int i = 0; i < 4; ++i)
#pragma unroll
            for (int r = 0; r < 4; ++r) zsh[hq - 2][i * 16 + mg + r][zn] += acc[i][r];
        }
        st_rel(&st[6 + (hq - 2)], (u32)(t + 1));
      }

      // ---- pointwise + publish (waves 4,5 only) ----
      if (hq < 2) {
        spin_ge(&st[6], (u32)(t + 1));
        spin_ge(&st[7], (u32)(t + 1));
        spin_ge(&st[2], (u32)(t + 1));
        spin_ge(&st[3], (u32)(t + 1));
        const int cb = t & 1;
        float hn[2];
#pragma unroll
        for (int jj = 0; jj < 2; ++jj) {
          const int col = pc + jj;
          const float zi = zsx[cb][0][prow][col]      + zsx[cb][1][prow][col]      + zsh[0][prow][col]      + zsh[1][prow][col]      + bz[jj][0];
          const float zj = zsx[cb][0][prow][4 + col]  + zsx[cb][1][prow][4 + col]  + zsh[0][prow][4 + col]  + zsh[1][prow][4 + col]  + bz[jj][1];
          const float zf = zsx[cb][0][prow][8 + col]  + zsx[cb][1][prow][8 + col]  + zsh[0][prow][8 + col]  + zsh[1][prow][8 + col]  + bz[jj][2];
          const float zo = zsx[cb][0][prow][12 + col] + zsx[cb][1][prow][12 + col] + zsh[0][prow][12 + col] + zsh[1][prow][12 + col] + bz[jj][3];
          const float si = 1.f / (1.f + __expf(-zi));
          const float tj = tanhf(zj);
          const float sf = 1.f / (1.f + __expf(-(zf + 1.0f)));  // FORGET_BIAS = 1
          const float so = 1.f / (1.f + __expf(-zo));
          const float cn = creg[jj] * sf + si * tj;
          hn[jj] = tanhf(cn) * so;
          creg[jj] = cn;
        }
        float2 ov = {hn[0], hn[1]};
        *reinterpret_cast<float2*>(out + ((size_t)prow * NT + t) * NH + gc0) = ov;
        if (t < NT - 1) {
          u32 hv = (u32)f2bf(hn[0]) | ((u32)f2bf(hn[1]) << 16);
          __hip_atomic_store(
              reinterpret_cast<u32*>(hseq + (size_t)(t + 1) * NBH + (size_t)prow * NH + gc0),
              hv, __ATOMIC_RELAXED, __HIP_MEMORY_SCOPE_AGENT);
        }
        asm volatile("s_waitcnt vmcnt(0)" ::: "memory");  // h at LLC
        st_rel(&st[8 + hq], (u32)(t + 1));
        if (hq == 0 && t < NT - 1) {
          spin_ge(&st[9], (u32)(t + 1));  // wave 5 drained too
          if (lane == 0)
            __hip_atomic_store(&flags[(size_t)(t + 1) * 256 + b], 1u,
                               __ATOMIC_RELAXED, __HIP_MEMORY_SCOPE_AGENT);
        }
      }
      // waves 6,7 fall through and pre-poll step t+1 while 4,5 finish t
    }
  }
}

extern "C" void kernel_launch(void* const* d_in, const int* in_sizes, int n_in,
                              void* d_out, int out_size, void* d_ws, size_t ws_size,
                              hipStream_t stream) {
  const float* x = (const float*)d_in[0];
  const float* W = (const float*)d_in[1];
  const float* bias = (const float*)d_in[2];
  float* out = (float*)d_out;

  char* ws = (char*)d_ws;
  u16* xb = (u16*)(ws);                                  // 16 MiB
  u16* wt_blk = (u16*)(ws + 16777216);                   // 32 MiB
  u16* hseq = (u16*)(ws + 50331648);                     // 16 MiB
  u32* flags = (u32*)(ws + 67108864);                    // 128 KiB

  hipMemsetAsync(flags, 0, NT * 256 * sizeof(u32), stream);  // per-replay

  lstm_cvt_x<<<(NB * NT * NF) / (256 * 4), 256, 0, stream>>>(x, xb);
  lstm_prep_w<<<dim3(NG / 32, NK / 32), 256, 0, stream>>>(W, wt_blk);

  hipFuncSetAttribute((const void*)lstm_persist,
                      hipFuncAttributeMaxDynamicSharedMemorySize, SMEM_BYTES);

  void* args[] = {(void*)&xb, (void*)&hseq, (void*)&wt_blk, (void*)&bias,
                  (void*)&out, (void*)&flags};
  hipLaunchCooperativeKernel((void*)lstm_persist, dim3(256), dim3(512), args,
                             SMEM_BYTES, stream);
}